// Round 5
// baseline (83.445 us; speedup 1.0000x reference)
//
#include <hip/hip_runtime.h>
#include <math.h>

// Problem constants (from reference)
constexpr int BATCH = 512;
constexpr int NC    = 10;
constexpr int RR    = 512;   // NUM_ROUTES
constexpr int CI    = 8;     // IN_CHANNELS
constexpr int CO    = 16;    // OUT_CHANNELS

constexpr int TPB = 64;          // ONE wave per block -> no cross-wave combines
constexpr int RPT = RR / TPB;    // 8 routes per thread

// One block (= one wave) per (b, c). Thread t owns routes t + k*64, k=0..7.
// u_hat[b,c,r,o] = sum_i x[b,r,i] * route_weights[c, b, i, o]
//   (weight's R-slot indexed by b — the reference's broadcasting quirk)
__global__ __launch_bounds__(TPB, 2) void caps_route_kernel(
    const float* __restrict__ x,    // (BATCH, RR, CI)
    const float* __restrict__ rw,   // (NC, RR, CI, CO)
    float* __restrict__ out)        // (BATCH, NC, CO)
{
    const int blk  = blockIdx.x;         // 0 .. BATCH*NC-1
    const int b    = blk / NC;
    const int c    = blk - b * NC;
    const int t    = threadIdx.x;        // 0..63 == lane

    __shared__ __align__(16) float W[CI][CO];         // 512 B, broadcast reads

    // Load W = route_weights[c, b, :, :] (128 floats, 2 per thread)
    {
        const size_t base = ((size_t)c * RR + b) * (CI * CO);
        ((float*)W)[t]      = rw[base + t];
        ((float*)W)[t + 64] = rw[base + t + 64];
    }
    __syncthreads();   // single wave: effectively free

    // ---- load x rows (coalesced float4) ----
    float xs[RPT][CI];
    #pragma unroll
    for (int k = 0; k < RPT; ++k) {
        const float4* xp = (const float4*)(x + ((size_t)b * RR + t + k * TPB) * CI);
        float4 a0 = xp[0], a1 = xp[1];
        xs[k][0]=a0.x; xs[k][1]=a0.y; xs[k][2]=a0.z; xs[k][3]=a0.w;
        xs[k][4]=a1.x; xs[k][5]=a1.y; xs[k][6]=a1.z; xs[k][7]=a1.w;
    }

    // ---- u_hat for 8 owned routes, in registers ----
    float u[RPT][CO];
    #pragma unroll
    for (int k = 0; k < RPT; ++k)
        #pragma unroll
        for (int o = 0; o < CO; ++o) u[k][o] = 0.f;

    #pragma unroll
    for (int i = 0; i < CI; ++i) {
        const float4* Wrow = (const float4*)&W[i][0];
        float4 wa = Wrow[0], wb = Wrow[1], wc = Wrow[2], wd = Wrow[3];
        #pragma unroll
        for (int k = 0; k < RPT; ++k) {
            const float xv = xs[k][i];
            u[k][0]  = fmaf(xv, wa.x, u[k][0]);
            u[k][1]  = fmaf(xv, wa.y, u[k][1]);
            u[k][2]  = fmaf(xv, wa.z, u[k][2]);
            u[k][3]  = fmaf(xv, wa.w, u[k][3]);
            u[k][4]  = fmaf(xv, wb.x, u[k][4]);
            u[k][5]  = fmaf(xv, wb.y, u[k][5]);
            u[k][6]  = fmaf(xv, wb.z, u[k][6]);
            u[k][7]  = fmaf(xv, wb.w, u[k][7]);
            u[k][8]  = fmaf(xv, wc.x, u[k][8]);
            u[k][9]  = fmaf(xv, wc.y, u[k][9]);
            u[k][10] = fmaf(xv, wc.z, u[k][10]);
            u[k][11] = fmaf(xv, wc.w, u[k][11]);
            u[k][12] = fmaf(xv, wd.x, u[k][12]);
            u[k][13] = fmaf(xv, wd.y, u[k][13]);
            u[k][14] = fmaf(xv, wd.z, u[k][14]);
            u[k][15] = fmaf(xv, wd.w, u[k][15]);
        }
    }

    float logit[RPT];
    #pragma unroll
    for (int k = 0; k < RPT; ++k) logit[k] = 0.f;

    float num[CO];     // s_j after scaling
    float ks = 0.f;    // squash scale: v[o] = num[o] * ks

    for (int iter = 0; iter < 3; ++iter) {
        // ---- per-thread partials: p[o] = sum_k e_k * u[k][o], den = sum e ----
        float p[CO];
        float den = 0.f;
        if (iter == 0) {
            // b == 0 -> softmax uniform; fold 1/512 in at the scale step
            #pragma unroll
            for (int o = 0; o < CO; ++o) {
                float a = (u[0][o] + u[1][o]) + (u[2][o] + u[3][o]);
                float d = (u[4][o] + u[5][o]) + (u[6][o] + u[7][o]);
                p[o] = a + d;
            }
        } else {
            float e[RPT];
            #pragma unroll
            for (int k = 0; k < RPT; ++k) e[k] = __expf(logit[k]);  // |logit| bounded, no overflow
            den = ((e[0] + e[1]) + (e[2] + e[3])) + ((e[4] + e[5]) + (e[6] + e[7]));
            #pragma unroll
            for (int o = 0; o < CO; ++o) {
                float a = fmaf(e[0], u[0][o], e[1] * u[1][o]);
                float d = fmaf(e[2], u[2][o], e[3] * u[3][o]);
                float f = fmaf(e[4], u[4][o], e[5] * u[5][o]);
                float g = fmaf(e[6], u[6][o], e[7] * u[7][o]);
                p[o] = (a + d) + (f + g);
            }
        }

        // ---- value-split butterfly over 64 lanes (17 shuffles) ----
        // KEEP the half matching our lane bit, SEND the other half.
        // After 4 split stages lane holds element (lane>>2)&15;
        // xor2/xor1 complete the full 512-route sum (single wave owns all).
        float q1[8];
        {
            const bool hi = (t & 32) != 0;
            #pragma unroll
            for (int k = 0; k < 8; ++k) {
                float keep = hi ? p[8 + k] : p[k];
                float send = hi ? p[k]     : p[8 + k];
                q1[k] = keep + __shfl_xor(send, 32, 64);
            }
        }
        float q2[4];
        {
            const bool hi = (t & 16) != 0;
            #pragma unroll
            for (int k = 0; k < 4; ++k) {
                float keep = hi ? q1[4 + k] : q1[k];
                float send = hi ? q1[k]     : q1[4 + k];
                q2[k] = keep + __shfl_xor(send, 16, 64);
            }
        }
        float q3[2];
        {
            const bool hi = (t & 8) != 0;
            #pragma unroll
            for (int k = 0; k < 2; ++k) {
                float keep = hi ? q2[2 + k] : q2[k];
                float send = hi ? q2[k]     : q2[2 + k];
                q3[k] = keep + __shfl_xor(send, 8, 64);
            }
        }
        float q4;
        {
            const bool hi = (t & 4) != 0;
            float keep = hi ? q3[1] : q3[0];
            float send = hi ? q3[0] : q3[1];
            q4 = keep + __shfl_xor(send, 4, 64);
        }
        q4 += __shfl_xor(q4, 2, 64);
        q4 += __shfl_xor(q4, 1, 64);

        // denominator butterfly -> every lane holds the full sum (no LDS)
        if (iter != 0) {
            den += __shfl_xor(den, 32, 64);
            den += __shfl_xor(den, 16, 64);
            den += __shfl_xor(den,  8, 64);
            den += __shfl_xor(den,  4, 64);
            den += __shfl_xor(den,  2, 64);
            den += __shfl_xor(den,  1, 64);
        } else {
            den = (float)RR;
        }

        // ---- broadcast num[o] from lane 4*o (16 independent bpermutes) ----
        #pragma unroll
        for (int o = 0; o < CO; ++o)
            num[o] = __shfl(q4, o << 2, 64);

        const float inv = 1.0f / den;

        // ---- SCALE FIRST (overflow-safe), then squash ----
        #pragma unroll
        for (int o = 0; o < CO; ++o) num[o] *= inv;

        float nsq = 0.f;
        #pragma unroll
        for (int o = 0; o < CO; ++o) nsq = fmaf(num[o], num[o], nsq);
        const float nrm = sqrtf(nsq);
        ks = nrm / (1.0f + nsq);             // v[o] = num[o] * ks

        // ---- b_ij += u . v  (skip on last iter) ----
        if (iter < 2) {
            #pragma unroll
            for (int k = 0; k < RPT; ++k) {
                float d = 0.f;
                #pragma unroll
                for (int o = 0; o < CO; ++o) d = fmaf(u[k][o], num[o], d);
                logit[k] = fmaf(d, ks, logit[k]);
            }
        }
    }

    // ---- write v = num * ks: 4 lanes store one float4 each ----
    if (t < 4) {
        float4* op = (float4*)(out + ((size_t)b * NC + c) * CO);
        op[t] = make_float4(num[4*t+0]*ks, num[4*t+1]*ks,
                            num[4*t+2]*ks, num[4*t+3]*ks);
    }
}

extern "C" void kernel_launch(void* const* d_in, const int* in_sizes, int n_in,
                              void* d_out, int out_size, void* d_ws, size_t ws_size,
                              hipStream_t stream) {
    const float* x  = (const float*)d_in[0];   // (512, 512, 8)
    const float* rw = (const float*)d_in[1];   // (10, 512, 8, 16)
    float* out = (float*)d_out;                // (512, 10, 16)

    dim3 grid(BATCH * NC);
    dim3 block(TPB);
    caps_route_kernel<<<grid, block, 0, stream>>>(x, rw, out);
}

// Round 6
// 24.762 us; speedup vs baseline: 3.3698x; 3.3698x over previous
//
#include <hip/hip_runtime.h>
#include <math.h>

// Problem constants (from reference)
constexpr int BATCH = 512;
constexpr int NC    = 10;
constexpr int RR    = 512;   // NUM_ROUTES
constexpr int CI    = 8;     // IN_CHANNELS
constexpr int CO    = 16;    // OUT_CHANNELS

constexpr int TPB = 64;          // ONE wave per block -> no barriers, no cross-wave
constexpr int RPT = RR / TPB;    // 8 routes per thread

// One block (= one wave) per (b, c). Thread t owns routes t + k*64, k=0..7.
// u_hat[b,c,r,o] = sum_i x[b,r,i] * route_weights[c, b, i, o]
//   (weight's R-slot indexed by b — the reference's broadcasting quirk)
//
// KEY: u_hat is never materialized. All routing math factors through W:
//   s_j      = (sum_r c_r x_r) . W      -> reduce the 8-vector y, not 16-vector
//   u_r . v  = x_r . (W v)              -> one shared Wv per iteration
// Register state: xs[8][8] + logit[8] + temps ~ 120 floats -> no spill.
__global__ __launch_bounds__(TPB) void caps_route_kernel(
    const float* __restrict__ x,    // (BATCH, RR, CI)
    const float* __restrict__ rw,   // (NC, RR, CI, CO)
    float* __restrict__ out)        // (BATCH, NC, CO)
{
    const int blk  = blockIdx.x;         // 0 .. BATCH*NC-1
    const int b    = blk / NC;
    const int c    = blk - b * NC;
    const int t    = threadIdx.x;        // 0..63 == lane

    __shared__ __align__(16) float W[CI][CO];         // 512 B, broadcast reads

    // Load W = route_weights[c, b, :, :] (128 floats, 2 per thread)
    {
        const size_t base = ((size_t)c * RR + b) * (CI * CO);
        ((float*)W)[t]      = rw[base + t];
        ((float*)W)[t + 64] = rw[base + t + 64];
    }
    __syncthreads();   // single wave: cheap

    // ---- load x rows (coalesced float4) ----
    float xs[RPT][CI];
    #pragma unroll
    for (int k = 0; k < RPT; ++k) {
        const float4* xp = (const float4*)(x + ((size_t)b * RR + t + k * TPB) * CI);
        float4 a0 = xp[0], a1 = xp[1];
        xs[k][0]=a0.x; xs[k][1]=a0.y; xs[k][2]=a0.z; xs[k][3]=a0.w;
        xs[k][4]=a1.x; xs[k][5]=a1.y; xs[k][6]=a1.z; xs[k][7]=a1.w;
    }

    float logit[RPT];
    #pragma unroll
    for (int k = 0; k < RPT; ++k) logit[k] = 0.f;

    float num[CO];     // s_j after scaling (all lanes)
    float ks = 0.f;    // squash scale: v[o] = num[o] * ks

    for (int iter = 0; iter < 3; ++iter) {
        // ---- per-thread e-weighted x sum: yl[i] = sum_k e_k xs[k][i] ----
        float yl[CI];
        float den = 0.f;
        if (iter == 0) {
            // b == 0 -> softmax uniform; fold 1/512 in at the scale step
            #pragma unroll
            for (int i = 0; i < CI; ++i) {
                float a = (xs[0][i] + xs[1][i]) + (xs[2][i] + xs[3][i]);
                float d = (xs[4][i] + xs[5][i]) + (xs[6][i] + xs[7][i]);
                yl[i] = a + d;
            }
        } else {
            float e[RPT];
            #pragma unroll
            for (int k = 0; k < RPT; ++k) e[k] = __expf(logit[k]);  // |logit| <~ 44
            den = ((e[0] + e[1]) + (e[2] + e[3])) + ((e[4] + e[5]) + (e[6] + e[7]));
            #pragma unroll
            for (int i = 0; i < CI; ++i) {
                float a = fmaf(e[0], xs[0][i], e[1] * xs[1][i]);
                float d = fmaf(e[2], xs[2][i], e[3] * xs[3][i]);
                float f = fmaf(e[4], xs[4][i], e[5] * xs[5][i]);
                float g = fmaf(e[6], xs[6][i], e[7] * xs[7][i]);
                yl[i] = (a + d) + (f + g);
            }
        }

        // ---- value-split butterfly on 8-vector (10 shuffles) ----
        // KEEP the half matching our lane bit, SEND the other half.
        // bit5 -> elem bit2, bit4 -> elem bit1, bit3 -> elem bit0;
        // xor4/2/1 complete the sum over the remaining lane bits.
        float s1[4];
        {
            const bool hi = (t & 32) != 0;
            #pragma unroll
            for (int k = 0; k < 4; ++k) {
                float keep = hi ? yl[4 + k] : yl[k];
                float send = hi ? yl[k]     : yl[4 + k];
                s1[k] = keep + __shfl_xor(send, 32, 64);
            }
        }
        float s2[2];
        {
            const bool hi = (t & 16) != 0;
            #pragma unroll
            for (int k = 0; k < 2; ++k) {
                float keep = hi ? s1[2 + k] : s1[k];
                float send = hi ? s1[k]     : s1[2 + k];
                s2[k] = keep + __shfl_xor(send, 16, 64);
            }
        }
        float s3;
        {
            const bool hi = (t & 8) != 0;
            float keep = hi ? s2[1] : s2[0];
            float send = hi ? s2[0] : s2[1];
            s3 = keep + __shfl_xor(send, 8, 64);
        }
        s3 += __shfl_xor(s3, 4, 64);
        s3 += __shfl_xor(s3, 2, 64);
        s3 += __shfl_xor(s3, 1, 64);
        // y[e] now lives (replicated) in lanes 8e..8e+7

        // denominator butterfly -> every lane holds the full sum
        if (iter != 0) {
            den += __shfl_xor(den, 32, 64);
            den += __shfl_xor(den, 16, 64);
            den += __shfl_xor(den,  8, 64);
            den += __shfl_xor(den,  4, 64);
            den += __shfl_xor(den,  2, 64);
            den += __shfl_xor(den,  1, 64);
        } else {
            den = (float)RR;
        }

        // ---- broadcast y[0..7] to all lanes (8 readlane broadcasts) ----
        float y[CI];
        #pragma unroll
        for (int i = 0; i < CI; ++i)
            y[i] = __shfl(s3, i << 3, 64);

        // ---- num[o] = sum_i y[i] * W[i][o]  (broadcast LDS float4 reads) ----
        {
            float4 a0 = make_float4(0.f,0.f,0.f,0.f);
            float4 a1 = a0, a2 = a0, a3 = a0;
            #pragma unroll
            for (int i = 0; i < CI; ++i) {
                const float4* Wr = (const float4*)&W[i][0];
                float4 w0 = Wr[0], w1 = Wr[1], w2 = Wr[2], w3 = Wr[3];
                const float yi = y[i];
                a0.x = fmaf(yi, w0.x, a0.x); a0.y = fmaf(yi, w0.y, a0.y);
                a0.z = fmaf(yi, w0.z, a0.z); a0.w = fmaf(yi, w0.w, a0.w);
                a1.x = fmaf(yi, w1.x, a1.x); a1.y = fmaf(yi, w1.y, a1.y);
                a1.z = fmaf(yi, w1.z, a1.z); a1.w = fmaf(yi, w1.w, a1.w);
                a2.x = fmaf(yi, w2.x, a2.x); a2.y = fmaf(yi, w2.y, a2.y);
                a2.z = fmaf(yi, w2.z, a2.z); a2.w = fmaf(yi, w2.w, a2.w);
                a3.x = fmaf(yi, w3.x, a3.x); a3.y = fmaf(yi, w3.y, a3.y);
                a3.z = fmaf(yi, w3.z, a3.z); a3.w = fmaf(yi, w3.w, a3.w);
            }
            num[0]=a0.x; num[1]=a0.y; num[2]=a0.z; num[3]=a0.w;
            num[4]=a1.x; num[5]=a1.y; num[6]=a1.z; num[7]=a1.w;
            num[8]=a2.x; num[9]=a2.y; num[10]=a2.z; num[11]=a2.w;
            num[12]=a3.x; num[13]=a3.y; num[14]=a3.z; num[15]=a3.w;
        }

        const float inv = 1.0f / den;

        // ---- SCALE FIRST (overflow-safe), then squash ----
        #pragma unroll
        for (int o = 0; o < CO; ++o) num[o] *= inv;

        float nsq = 0.f;
        #pragma unroll
        for (int o = 0; o < CO; ++o) nsq = fmaf(num[o], num[o], nsq);
        const float nrm = sqrtf(nsq);
        ks = nrm / (1.0f + nsq);             // v[o] = num[o] * ks

        // ---- logit[k] += (xs[k] . Wv) * ks, Wv[i] = sum_o W[i][o]*num[o] ----
        if (iter < 2) {
            float wv[CI];
            #pragma unroll
            for (int i = 0; i < CI; ++i) {
                const float4* Wr = (const float4*)&W[i][0];
                float4 w0 = Wr[0], w1 = Wr[1], w2 = Wr[2], w3 = Wr[3];
                float d0 = fmaf(w0.x, num[0],  w0.y * num[1]);
                float d1 = fmaf(w0.z, num[2],  w0.w * num[3]);
                float d2 = fmaf(w1.x, num[4],  w1.y * num[5]);
                float d3 = fmaf(w1.z, num[6],  w1.w * num[7]);
                float d4 = fmaf(w2.x, num[8],  w2.y * num[9]);
                float d5 = fmaf(w2.z, num[10], w2.w * num[11]);
                float d6 = fmaf(w3.x, num[12], w3.y * num[13]);
                float d7 = fmaf(w3.z, num[14], w3.w * num[15]);
                wv[i] = ((d0 + d1) + (d2 + d3)) + ((d4 + d5) + (d6 + d7));
            }
            #pragma unroll
            for (int k = 0; k < RPT; ++k) {
                float d = 0.f;
                #pragma unroll
                for (int i = 0; i < CI; ++i) d = fmaf(xs[k][i], wv[i], d);
                logit[k] = fmaf(d, ks, logit[k]);
            }
        }
    }

    // ---- write v = num * ks: 4 lanes store one float4 each ----
    if (t < 4) {
        float4* op = (float4*)(out + ((size_t)b * NC + c) * CO);
        op[t] = make_float4(num[4*t+0]*ks, num[4*t+1]*ks,
                            num[4*t+2]*ks, num[4*t+3]*ks);
    }
}

extern "C" void kernel_launch(void* const* d_in, const int* in_sizes, int n_in,
                              void* d_out, int out_size, void* d_ws, size_t ws_size,
                              hipStream_t stream) {
    const float* x  = (const float*)d_in[0];   // (512, 512, 8)
    const float* rw = (const float*)d_in[1];   // (10, 512, 8, 16)
    float* out = (float*)d_out;                // (512, 10, 16)

    dim3 grid(BATCH * NC);
    dim3 block(TPB);
    caps_route_kernel<<<grid, block, 0, stream>>>(x, rw, out);
}